// Round 1
// baseline (551.435 us; speedup 1.0000x reference)
//
#include <hip/hip_runtime.h>
#include <math.h>

#define N_NODES 100000
#define N_EDGES 1600000
#define DIN 128
#define DH 64
#define DOUT 40

// ---------------- CSR build ----------------

__global__ void k_count(const int* __restrict__ dst, int* __restrict__ deg) {
    int e = blockIdx.x * 256 + threadIdx.x;
    if (e < N_EDGES) atomicAdd(&deg[dst[e]], 1);
}

// 1024 elements per block (256 threads x 4), exclusive scan within block + block sums
__global__ void k_scan1(const int* __restrict__ deg, int* __restrict__ rs,
                        int* __restrict__ bsum) {
    __shared__ int lds[256];
    int t = threadIdx.x, b = blockIdx.x;
    int base = b * 1024 + t * 4;
    int v0 = (base + 0 < N_NODES) ? deg[base + 0] : 0;
    int v1 = (base + 1 < N_NODES) ? deg[base + 1] : 0;
    int v2 = (base + 2 < N_NODES) ? deg[base + 2] : 0;
    int v3 = (base + 3 < N_NODES) ? deg[base + 3] : 0;
    int s = v0 + v1 + v2 + v3;
    lds[t] = s;
    __syncthreads();
    for (int off = 1; off < 256; off <<= 1) {
        int add = (t >= off) ? lds[t - off] : 0;
        __syncthreads();
        lds[t] += add;
        __syncthreads();
    }
    int excl = lds[t] - s;
    if (t == 255) bsum[b] = lds[255];
    if (base + 0 < N_NODES) rs[base + 0] = excl;
    if (base + 1 < N_NODES) rs[base + 1] = excl + v0;
    if (base + 2 < N_NODES) rs[base + 2] = excl + v0 + v1;
    if (base + 3 < N_NODES) rs[base + 3] = excl + v0 + v1 + v2;
}

__global__ void k_scan2(int* __restrict__ bsum) {  // single block, 128 threads
    __shared__ int lds[128];
    int t = threadIdx.x;
    int v = (t < 98) ? bsum[t] : 0;
    lds[t] = v;
    __syncthreads();
    for (int off = 1; off < 128; off <<= 1) {
        int add = (t >= off) ? lds[t - off] : 0;
        __syncthreads();
        lds[t] += add;
        __syncthreads();
    }
    if (t < 98) bsum[t] = lds[t] - v;
}

__global__ void k_finalize(int* __restrict__ rs, const int* __restrict__ bsum,
                           const int* __restrict__ deg, float* __restrict__ dinv,
                           int* __restrict__ cursor) {
    int i = blockIdx.x * 256 + threadIdx.x;
    if (i < N_NODES) {
        rs[i] += bsum[i >> 10];
        dinv[i] = rsqrtf((float)deg[i] + 1.0f);
        cursor[i] = 0;
    }
}

__global__ void k_fill(const int* __restrict__ src, const int* __restrict__ dst,
                       const int* __restrict__ rs, int* __restrict__ cursor,
                       int* __restrict__ csr) {
    int e = blockIdx.x * 256 + threadIdx.x;
    if (e < N_EDGES) {
        int d = dst[e];
        int p = atomicAdd(&cursor[d], 1);
        csr[rs[d] + p] = src[e];
    }
}

// ---------------- GEMM1: h1s = (x @ W1) * dinv[row]  [N,64] ----------------
// BM=64 rows, full K=128, full N=64. 256 threads, 4x4 micro-tile each.

__global__ __launch_bounds__(256) void k_gemm1(const float* __restrict__ x,
                                               const float* __restrict__ W1,
                                               const float* __restrict__ dinv,
                                               float* __restrict__ h1s) {
    __shared__ float xs[64 * 132];     // padded stride 132 to dodge bank conflicts
    __shared__ float wsh[DIN * DH];    // 128x64
    int t = threadIdx.x;
    int row0 = blockIdx.x * 64;

    // stage x tile: 64 rows x 128 cols = 8192 floats, 8 float4 per thread
    for (int it = 0; it < 8; ++it) {
        int idx = (it * 256 + t) * 4;
        int r = idx >> 7, c = idx & 127;
        float4 v = make_float4(0.f, 0.f, 0.f, 0.f);
        if (row0 + r < N_NODES) v = *(const float4*)&x[(size_t)(row0 + r) * DIN + c];
        *(float4*)&xs[r * 132 + c] = v;
    }
    // stage W1: 8192 floats
    for (int it = 0; it < 8; ++it) {
        int idx = (it * 256 + t) * 4;
        *(float4*)&wsh[idx] = *(const float4*)&W1[idx];
    }
    __syncthreads();

    int tr = t & 15;  // feature group: features tr*4..tr*4+3
    int tc = t >> 4;  // row group: rows tc*4..tc*4+3
    float acc[4][4] = {};
    for (int k = 0; k < DIN; ++k) {
        float4 wv = *(const float4*)&wsh[k * DH + tr * 4];
#pragma unroll
        for (int i = 0; i < 4; ++i) {
            float xv = xs[(tc * 4 + i) * 132 + k];
            acc[i][0] += xv * wv.x;
            acc[i][1] += xv * wv.y;
            acc[i][2] += xv * wv.z;
            acc[i][3] += xv * wv.w;
        }
    }
#pragma unroll
    for (int i = 0; i < 4; ++i) {
        int row = row0 + tc * 4 + i;
        if (row < N_NODES) {
            float dv = dinv[row];
            float4 o = make_float4(acc[i][0] * dv, acc[i][1] * dv,
                                   acc[i][2] * dv, acc[i][3] * dv);
            *(float4*)&h1s[(size_t)row * DH + tr * 4] = o;
        }
    }
}

// ---------------- agg1: h1 = relu(dinv*(sum h1s[src] + h1s[n]) + b1) ----------------
// one 64-lane wave per node; lane = feature

__global__ __launch_bounds__(256) void k_agg1(const float* __restrict__ h1s,
                                              const int* __restrict__ rs,
                                              const int* __restrict__ deg,
                                              const int* __restrict__ csr,
                                              const float* __restrict__ dinv,
                                              const float* __restrict__ b1,
                                              float* __restrict__ h1) {
    int node = blockIdx.x * 4 + (threadIdx.x >> 6);
    int lane = threadIdx.x & 63;
    if (node >= N_NODES) return;
    float acc = h1s[(size_t)node * DH + lane];  // self-loop term
    int s0 = rs[node];
    int d = deg[node];
    for (int j = 0; j < d; ++j) {
        int s = csr[s0 + j];
        acc += h1s[(size_t)s * DH + lane];
    }
    float v = acc * dinv[node] + b1[lane];
    h1[(size_t)node * DH + lane] = fmaxf(v, 0.f);
}

// ---------------- GEMM2: h2s = (h1 @ W2) * dinv[row]  [N,40] ----------------
// BM=64 rows, K=64, N=40. 256 threads, 2x5 micro-tile.

__global__ __launch_bounds__(256) void k_gemm2(const float* __restrict__ h1,
                                               const float* __restrict__ W2,
                                               const float* __restrict__ dinv,
                                               float* __restrict__ h2s) {
    __shared__ float xs[64 * 68];
    __shared__ float wsh[DH * DOUT];  // 64*40 = 2560
    int t = threadIdx.x;
    int row0 = blockIdx.x * 64;

    for (int it = 0; it < 4; ++it) {  // 64x64 = 4096 floats
        int idx = (it * 256 + t) * 4;
        int r = idx >> 6, c = idx & 63;
        float4 v = make_float4(0.f, 0.f, 0.f, 0.f);
        if (row0 + r < N_NODES) v = *(const float4*)&h1[(size_t)(row0 + r) * DH + c];
        *(float4*)&xs[r * 68 + c] = v;
    }
    for (int idx = t * 4; idx < DH * DOUT; idx += 1024) {
        *(float4*)&wsh[idx] = *(const float4*)&W2[idx];
    }
    __syncthreads();

    int fg = t & 7;   // 8 groups x 5 features
    int rg = t >> 3;  // 32 groups x 2 rows
    float acc[2][5] = {};
    for (int k = 0; k < DH; ++k) {
        float x0 = xs[(rg * 2 + 0) * 68 + k];
        float x1 = xs[(rg * 2 + 1) * 68 + k];
#pragma unroll
        for (int j = 0; j < 5; ++j) {
            float w = wsh[k * DOUT + fg * 5 + j];
            acc[0][j] += x0 * w;
            acc[1][j] += x1 * w;
        }
    }
#pragma unroll
    for (int i = 0; i < 2; ++i) {
        int row = row0 + rg * 2 + i;
        if (row < N_NODES) {
            float dv = dinv[row];
#pragma unroll
            for (int j = 0; j < 5; ++j)
                h2s[(size_t)row * DOUT + fg * 5 + j] = acc[i][j] * dv;
        }
    }
}

// ---------------- agg2 + bias + log_softmax ----------------
// one 64-lane wave per node; lanes 0..39 hold features

__global__ __launch_bounds__(256) void k_agg2(const float* __restrict__ h2s,
                                              const int* __restrict__ rs,
                                              const int* __restrict__ deg,
                                              const int* __restrict__ csr,
                                              const float* __restrict__ dinv,
                                              const float* __restrict__ b2,
                                              float* __restrict__ out) {
    int node = blockIdx.x * 4 + (threadIdx.x >> 6);
    int lane = threadIdx.x & 63;
    if (node >= N_NODES) return;
    float acc = (lane < DOUT) ? h2s[(size_t)node * DOUT + lane] : 0.f;
    int s0 = rs[node];
    int d = deg[node];
    for (int j = 0; j < d; ++j) {
        int s = csr[s0 + j];
        if (lane < DOUT) acc += h2s[(size_t)s * DOUT + lane];
    }
    float v = (lane < DOUT) ? acc * dinv[node] + b2[lane] : -INFINITY;
    float m = v;
    for (int off = 32; off; off >>= 1) m = fmaxf(m, __shfl_xor(m, off, 64));
    float ex = (lane < DOUT) ? expf(v - m) : 0.f;
    float sum = ex;
    for (int off = 32; off; off >>= 1) sum += __shfl_xor(sum, off, 64);
    float lse = m + logf(sum);
    if (lane < DOUT) out[(size_t)node * DOUT + lane] = v - lse;
}

// ---------------- launch ----------------

extern "C" void kernel_launch(void* const* d_in, const int* in_sizes, int n_in,
                              void* d_out, int out_size, void* d_ws, size_t ws_size,
                              hipStream_t stream) {
    const float* x  = (const float*)d_in[0];
    const float* W1 = (const float*)d_in[1];
    const float* b1 = (const float*)d_in[2];
    const float* W2 = (const float*)d_in[3];
    const float* b2 = (const float*)d_in[4];
    const int* eidx = (const int*)d_in[5];
    const int* srcp = eidx;
    const int* dstp = eidx + N_EDGES;
    float* out = (float*)d_out;

    char* w = (char*)d_ws;
    int* deg    = (int*)w;   w += sizeof(int) * N_NODES;
    int* rs     = (int*)w;   w += sizeof(int) * N_NODES;
    int* bsum   = (int*)w;   w += sizeof(int) * 128;
    int* cursor = (int*)w;   w += sizeof(int) * N_NODES;
    float* dinv = (float*)w; w += sizeof(float) * N_NODES;
    int* csr    = (int*)w;   w += sizeof(int) * N_EDGES;
    float* h1s  = (float*)w; w += sizeof(float) * (size_t)N_NODES * DH;
    float* h1   = (float*)w; w += sizeof(float) * (size_t)N_NODES * DH;
    float* h2s  = h1s;  // alias: h1s is dead once agg1 completes

    hipMemsetAsync(deg, 0, sizeof(int) * N_NODES, stream);
    k_count<<<(N_EDGES + 255) / 256, 256, 0, stream>>>(dstp, deg);
    k_scan1<<<(N_NODES + 1023) / 1024, 256, 0, stream>>>(deg, rs, bsum);
    k_scan2<<<1, 128, 0, stream>>>(bsum);
    k_finalize<<<(N_NODES + 255) / 256, 256, 0, stream>>>(rs, bsum, deg, dinv, cursor);
    k_fill<<<(N_EDGES + 255) / 256, 256, 0, stream>>>(srcp, dstp, rs, cursor, csr);
    k_gemm1<<<(N_NODES + 63) / 64, 256, 0, stream>>>(x, W1, dinv, h1s);
    k_agg1<<<(N_NODES + 3) / 4, 256, 0, stream>>>(h1s, rs, deg, csr, dinv, b1, h1);
    k_gemm2<<<(N_NODES + 63) / 64, 256, 0, stream>>>(h1, W2, dinv, h2s);
    k_agg2<<<(N_NODES + 3) / 4, 256, 0, stream>>>(h2s, rs, deg, csr, dinv, b2, out);
}

// Round 2
// 396.539 us; speedup vs baseline: 1.3906x; 1.3906x over previous
//
#include <hip/hip_runtime.h>
#include <math.h>

#define N_NODES 100000
#define N_EDGES 1600000
#define DIN 128
#define DH 64
#define DOUT 40

typedef unsigned short u16;

__device__ inline float bf2f(u16 u) {
    return __uint_as_float(((unsigned int)u) << 16);
}
__device__ inline u16 f2bf(float f) {
    unsigned int u = __float_as_uint(f);
    unsigned int r = (u + 0x7FFFu + ((u >> 16) & 1u)) >> 16;  // RNE
    return (u16)r;
}

// ---------------- CSR build ----------------

__global__ void k_count(const int* __restrict__ dst, int* __restrict__ deg) {
    int e = blockIdx.x * 256 + threadIdx.x;
    if (e < N_EDGES) atomicAdd(&deg[dst[e]], 1);
}

// 1024 elements per block (256 threads x 4), exclusive scan within block + block sums
__global__ void k_scan1(const int* __restrict__ deg, int* __restrict__ rs,
                        int* __restrict__ bsum) {
    __shared__ int lds[256];
    int t = threadIdx.x, b = blockIdx.x;
    int base = b * 1024 + t * 4;
    int v0 = (base + 0 < N_NODES) ? deg[base + 0] : 0;
    int v1 = (base + 1 < N_NODES) ? deg[base + 1] : 0;
    int v2 = (base + 2 < N_NODES) ? deg[base + 2] : 0;
    int v3 = (base + 3 < N_NODES) ? deg[base + 3] : 0;
    int s = v0 + v1 + v2 + v3;
    lds[t] = s;
    __syncthreads();
    for (int off = 1; off < 256; off <<= 1) {
        int add = (t >= off) ? lds[t - off] : 0;
        __syncthreads();
        lds[t] += add;
        __syncthreads();
    }
    int excl = lds[t] - s;
    if (t == 255) bsum[b] = lds[255];
    if (base + 0 < N_NODES) rs[base + 0] = excl;
    if (base + 1 < N_NODES) rs[base + 1] = excl + v0;
    if (base + 2 < N_NODES) rs[base + 2] = excl + v0 + v1;
    if (base + 3 < N_NODES) rs[base + 3] = excl + v0 + v1 + v2;
}

__global__ void k_scan2(int* __restrict__ bsum) {  // single block, 128 threads
    __shared__ int lds[128];
    int t = threadIdx.x;
    int v = (t < 98) ? bsum[t] : 0;
    lds[t] = v;
    __syncthreads();
    for (int off = 1; off < 128; off <<= 1) {
        int add = (t >= off) ? lds[t - off] : 0;
        __syncthreads();
        lds[t] += add;
        __syncthreads();
    }
    if (t < 98) bsum[t] = lds[t] - v;
}

__global__ void k_finalize(int* __restrict__ rs, const int* __restrict__ bsum,
                           const int* __restrict__ deg, float* __restrict__ dinv,
                           int* __restrict__ cursor) {
    int i = blockIdx.x * 256 + threadIdx.x;
    if (i < N_NODES) {
        int r = rs[i] + bsum[i >> 10];
        rs[i] = r;
        cursor[i] = r;  // absolute starting offset; fill atomically bumps this
        dinv[i] = rsqrtf((float)deg[i] + 1.0f);
    }
}

__global__ void k_fill(const int* __restrict__ src, const int* __restrict__ dst,
                       int* __restrict__ cursor, int* __restrict__ csr) {
    int e = blockIdx.x * 256 + threadIdx.x;
    if (e < N_EDGES) {
        int p = atomicAdd(&cursor[dst[e]], 1);
        csr[p] = src[e];
    }
}

// ---------------- GEMM1: h1s = bf16((x @ W1) * dinv[row])  [N,64] ----------------

__global__ __launch_bounds__(256) void k_gemm1(const float* __restrict__ x,
                                               const float* __restrict__ W1,
                                               const float* __restrict__ dinv,
                                               u16* __restrict__ h1s) {
    __shared__ float xs[64 * 132];
    __shared__ float wsh[DIN * DH];
    int t = threadIdx.x;
    int row0 = blockIdx.x * 64;

    for (int it = 0; it < 8; ++it) {
        int idx = (it * 256 + t) * 4;
        int r = idx >> 7, c = idx & 127;
        float4 v = make_float4(0.f, 0.f, 0.f, 0.f);
        if (row0 + r < N_NODES) v = *(const float4*)&x[(size_t)(row0 + r) * DIN + c];
        *(float4*)&xs[r * 132 + c] = v;
    }
    for (int it = 0; it < 8; ++it) {
        int idx = (it * 256 + t) * 4;
        *(float4*)&wsh[idx] = *(const float4*)&W1[idx];
    }
    __syncthreads();

    int tr = t & 15;
    int tc = t >> 4;
    float acc[4][4] = {};
    for (int k = 0; k < DIN; ++k) {
        float4 wv = *(const float4*)&wsh[k * DH + tr * 4];
#pragma unroll
        for (int i = 0; i < 4; ++i) {
            float xv = xs[(tc * 4 + i) * 132 + k];
            acc[i][0] += xv * wv.x;
            acc[i][1] += xv * wv.y;
            acc[i][2] += xv * wv.z;
            acc[i][3] += xv * wv.w;
        }
    }
#pragma unroll
    for (int i = 0; i < 4; ++i) {
        int row = row0 + tc * 4 + i;
        if (row < N_NODES) {
            float dv = dinv[row];
            ushort4 o;
            o.x = f2bf(acc[i][0] * dv);
            o.y = f2bf(acc[i][1] * dv);
            o.z = f2bf(acc[i][2] * dv);
            o.w = f2bf(acc[i][3] * dv);
            *(ushort4*)&h1s[(size_t)row * DH + tr * 4] = o;
        }
    }
}

// ---------------- agg1: h1 = relu(dinv*(sum h1s[src] + h1s[n]) + b1) ----------------
// one 64-lane wave per node; lane = feature. Indices coalesced via lane-load + shfl,
// gather loop unrolled x8 with independent accumulators for MLP.

__global__ __launch_bounds__(256) void k_agg1(const u16* __restrict__ h1s,
                                              const int* __restrict__ rs,
                                              const int* __restrict__ deg,
                                              const int* __restrict__ csr,
                                              const float* __restrict__ dinv,
                                              const float* __restrict__ b1,
                                              float* __restrict__ h1) {
    int node = blockIdx.x * 4 + (threadIdx.x >> 6);
    int lane = threadIdx.x & 63;
    if (node >= N_NODES) return;
    int s0 = rs[node];
    int d = deg[node];
    float a0 = bf2f(h1s[(size_t)node * DH + lane]);  // self-loop term
    float a1 = 0.f, a2 = 0.f, a3 = 0.f, a4 = 0.f, a5 = 0.f, a6 = 0.f, a7 = 0.f;
    for (int base = 0; base < d; base += 64) {
        int nn = d - base; if (nn > 64) nn = 64;
        int myidx = (lane < nn) ? csr[s0 + base + lane] : 0;
        int j = 0;
        for (; j + 8 <= nn; j += 8) {
            int i0 = __shfl(myidx, j + 0, 64); int i1 = __shfl(myidx, j + 1, 64);
            int i2 = __shfl(myidx, j + 2, 64); int i3 = __shfl(myidx, j + 3, 64);
            int i4 = __shfl(myidx, j + 4, 64); int i5 = __shfl(myidx, j + 5, 64);
            int i6 = __shfl(myidx, j + 6, 64); int i7 = __shfl(myidx, j + 7, 64);
            a0 += bf2f(h1s[(size_t)i0 * DH + lane]);
            a1 += bf2f(h1s[(size_t)i1 * DH + lane]);
            a2 += bf2f(h1s[(size_t)i2 * DH + lane]);
            a3 += bf2f(h1s[(size_t)i3 * DH + lane]);
            a4 += bf2f(h1s[(size_t)i4 * DH + lane]);
            a5 += bf2f(h1s[(size_t)i5 * DH + lane]);
            a6 += bf2f(h1s[(size_t)i6 * DH + lane]);
            a7 += bf2f(h1s[(size_t)i7 * DH + lane]);
        }
        for (; j < nn; ++j) {
            int s = __shfl(myidx, j, 64);
            a0 += bf2f(h1s[(size_t)s * DH + lane]);
        }
    }
    float acc = ((a0 + a1) + (a2 + a3)) + ((a4 + a5) + (a6 + a7));
    float v = acc * dinv[node] + b1[lane];
    h1[(size_t)node * DH + lane] = fmaxf(v, 0.f);
}

// ---------------- GEMM2: h2s = bf16((h1 @ W2) * dinv[row])  [N,64-padded] ----------------

__global__ __launch_bounds__(256) void k_gemm2(const float* __restrict__ h1,
                                               const float* __restrict__ W2,
                                               const float* __restrict__ dinv,
                                               u16* __restrict__ h2s) {
    __shared__ float xs[64 * 68];
    __shared__ float wsh[DH * DOUT];
    int t = threadIdx.x;
    int row0 = blockIdx.x * 64;

    for (int it = 0; it < 4; ++it) {
        int idx = (it * 256 + t) * 4;
        int r = idx >> 6, c = idx & 63;
        float4 v = make_float4(0.f, 0.f, 0.f, 0.f);
        if (row0 + r < N_NODES) v = *(const float4*)&h1[(size_t)(row0 + r) * DH + c];
        *(float4*)&xs[r * 68 + c] = v;
    }
    for (int idx = t * 4; idx < DH * DOUT; idx += 1024) {
        *(float4*)&wsh[idx] = *(const float4*)&W2[idx];
    }
    __syncthreads();

    int fg = t & 7;
    int rg = t >> 3;
    float acc[2][5] = {};
    for (int k = 0; k < DH; ++k) {
        float x0 = xs[(rg * 2 + 0) * 68 + k];
        float x1 = xs[(rg * 2 + 1) * 68 + k];
#pragma unroll
        for (int j = 0; j < 5; ++j) {
            float w = wsh[k * DOUT + fg * 5 + j];
            acc[0][j] += x0 * w;
            acc[1][j] += x1 * w;
        }
    }
#pragma unroll
    for (int i = 0; i < 2; ++i) {
        int row = row0 + rg * 2 + i;
        if (row < N_NODES) {
            float dv = dinv[row];
#pragma unroll
            for (int j = 0; j < 5; ++j)
                h2s[(size_t)row * 64 + fg * 5 + j] = f2bf(acc[i][j] * dv);
        }
    }
}

// ---------------- agg2 + bias + log_softmax ----------------
// h2s rows padded to 64 bf16 (128 B) so a gather never crosses a cacheline.

__global__ __launch_bounds__(256) void k_agg2(const u16* __restrict__ h2s,
                                              const int* __restrict__ rs,
                                              const int* __restrict__ deg,
                                              const int* __restrict__ csr,
                                              const float* __restrict__ dinv,
                                              const float* __restrict__ b2,
                                              float* __restrict__ out) {
    int node = blockIdx.x * 4 + (threadIdx.x >> 6);
    int lane = threadIdx.x & 63;
    if (node >= N_NODES) return;
    int s0 = rs[node];
    int d = deg[node];
    bool act = lane < DOUT;
    float a0 = act ? bf2f(h2s[(size_t)node * 64 + lane]) : 0.f;  // self-loop
    float a1 = 0.f, a2 = 0.f, a3 = 0.f, a4 = 0.f, a5 = 0.f, a6 = 0.f, a7 = 0.f;
    for (int base = 0; base < d; base += 64) {
        int nn = d - base; if (nn > 64) nn = 64;
        int myidx = (lane < nn) ? csr[s0 + base + lane] : 0;
        int j = 0;
        for (; j + 8 <= nn; j += 8) {
            int i0 = __shfl(myidx, j + 0, 64); int i1 = __shfl(myidx, j + 1, 64);
            int i2 = __shfl(myidx, j + 2, 64); int i3 = __shfl(myidx, j + 3, 64);
            int i4 = __shfl(myidx, j + 4, 64); int i5 = __shfl(myidx, j + 5, 64);
            int i6 = __shfl(myidx, j + 6, 64); int i7 = __shfl(myidx, j + 7, 64);
            if (act) {
                a0 += bf2f(h2s[(size_t)i0 * 64 + lane]);
                a1 += bf2f(h2s[(size_t)i1 * 64 + lane]);
                a2 += bf2f(h2s[(size_t)i2 * 64 + lane]);
                a3 += bf2f(h2s[(size_t)i3 * 64 + lane]);
                a4 += bf2f(h2s[(size_t)i4 * 64 + lane]);
                a5 += bf2f(h2s[(size_t)i5 * 64 + lane]);
                a6 += bf2f(h2s[(size_t)i6 * 64 + lane]);
                a7 += bf2f(h2s[(size_t)i7 * 64 + lane]);
            }
        }
        for (; j < nn; ++j) {
            int s = __shfl(myidx, j, 64);
            if (act) a0 += bf2f(h2s[(size_t)s * 64 + lane]);
        }
    }
    float acc = ((a0 + a1) + (a2 + a3)) + ((a4 + a5) + (a6 + a7));
    float v = act ? acc * dinv[node] + b2[lane] : -INFINITY;
    float m = v;
    for (int off = 32; off; off >>= 1) m = fmaxf(m, __shfl_xor(m, off, 64));
    float ex = act ? expf(v - m) : 0.f;
    float sum = ex;
    for (int off = 32; off; off >>= 1) sum += __shfl_xor(sum, off, 64);
    float lse = m + logf(sum);
    if (act) out[(size_t)node * DOUT + lane] = v - lse;
}

// ---------------- launch ----------------

extern "C" void kernel_launch(void* const* d_in, const int* in_sizes, int n_in,
                              void* d_out, int out_size, void* d_ws, size_t ws_size,
                              hipStream_t stream) {
    const float* x  = (const float*)d_in[0];
    const float* W1 = (const float*)d_in[1];
    const float* b1 = (const float*)d_in[2];
    const float* W2 = (const float*)d_in[3];
    const float* b2 = (const float*)d_in[4];
    const int* eidx = (const int*)d_in[5];
    const int* srcp = eidx;
    const int* dstp = eidx + N_EDGES;
    float* out = (float*)d_out;

    char* w = (char*)d_ws;
    int* deg    = (int*)w;   w += sizeof(int) * N_NODES;
    int* rs     = (int*)w;   w += sizeof(int) * N_NODES;
    int* bsum   = (int*)w;   w += sizeof(int) * 128;
    int* cursor = (int*)w;   w += sizeof(int) * N_NODES;
    float* dinv = (float*)w; w += sizeof(float) * N_NODES;
    int* csr    = (int*)w;   w += sizeof(int) * N_EDGES;
    u16* h1s    = (u16*)w;   w += sizeof(u16) * (size_t)N_NODES * DH;   // bf16 [N,64]
    float* h1   = (float*)w; w += sizeof(float) * (size_t)N_NODES * DH; // f32  [N,64]
    u16* h2s    = h1s;  // alias: h1s dead after agg1; h2s is bf16 [N,64-padded]

    hipMemsetAsync(deg, 0, sizeof(int) * N_NODES, stream);
    k_count<<<(N_EDGES + 255) / 256, 256, 0, stream>>>(dstp, deg);
    k_scan1<<<(N_NODES + 1023) / 1024, 256, 0, stream>>>(deg, rs, bsum);
    k_scan2<<<1, 128, 0, stream>>>(bsum);
    k_finalize<<<(N_NODES + 255) / 256, 256, 0, stream>>>(rs, bsum, deg, dinv, cursor);
    k_fill<<<(N_EDGES + 255) / 256, 256, 0, stream>>>(srcp, dstp, cursor, csr);
    k_gemm1<<<(N_NODES + 63) / 64, 256, 0, stream>>>(x, W1, dinv, h1s);
    k_agg1<<<(N_NODES + 3) / 4, 256, 0, stream>>>(h1s, rs, deg, csr, dinv, b1, h1);
    k_gemm2<<<(N_NODES + 63) / 64, 256, 0, stream>>>(h1, W2, dinv, h2s);
    k_agg2<<<(N_NODES + 3) / 4, 256, 0, stream>>>(h2s, rs, deg, csr, dinv, b2, out);
}